// Round 9
// baseline (206.275 us; speedup 1.0000x reference)
//
#include <hip/hip_runtime.h>

// ---------------------------------------------------------------------------
// DoReFa BasicBlock on MI355X: both 3x3 convs as exact int8 implicit GEMM.
//   acts   quantized to a_int in {0..3}       (value = a_int/3)
//   weights quantized to w_int in {-3,-1,1,3} (value = w_int/3)
//   conv_f32 = (sum a_int*w_int) / 9  -> folded into BN scale s = inv/9.
// Round 9: = round 8 with ONE fix: conv2's B pixel base was the padded
// CENTER (hh+1, ww+1) while loadB's tap offset is from the TOP-LEFT ->
// all conv2 reads shifted (+1,+1) -> absmax 56. Base is now (hh, ww).
//  (a) B never touches LDS: per-lane global loads from wqT1 (conv1) / a2T
//      (conv2) k-major layouts.
//  (b) wvm=1 waves defer quads(1,*) of tile t-1 past barrier t (anti-phase).
//  (c) handoff: vmcnt(0)+lgkm(0) + s_barrier once per K-tile.
// Layouts: a1 padded NHWC u8 [64][30][30][256];
//          wqT1 [144 kslot][256 chout][16B]; wq2 row-major [256][2304];
//          a2T [16 chslot][64*900 pix][16B].
// ---------------------------------------------------------------------------

#define ABUF 14745600
using i32x4 = __attribute__((ext_vector_type(4))) int;

__device__ __forceinline__ void gload16(const void* g, void* l) {
  typedef const __attribute__((address_space(1))) unsigned int* gp_t;
  typedef __attribute__((address_space(3))) unsigned int* lp_t;
  __builtin_amdgcn_global_load_lds((gp_t)g, (lp_t)l, 16, 0, 0);
}

// ---- fused pre-pass: blocks 0-255 aquant, 256-383 maxabs partials ---------
__device__ __forceinline__ int border_pix(int bp) {  // 0..115 -> hh*30+ww
  int hh, ww;
  if (bp < 30)      { hh = 0;       ww = bp; }
  else if (bp < 60) { hh = 29;      ww = bp - 30; }
  else if (bp < 88) { hh = bp - 59; ww = 0; }
  else              { hh = bp - 87; ww = 29; }
  return hh * 30 + ww;
}

__global__ void pre_k(const float* __restrict__ x, unsigned char* __restrict__ a1,
                      unsigned char* __restrict__ a2T,
                      const float* __restrict__ w1, const float* __restrict__ w2,
                      float* __restrict__ partial,
                      const float* g1, const float* b1, const float* m1, const float* v1,
                      const float* g2, const float* b2, const float* m2, const float* v2,
                      float* s1, float* t1, float* s2, float* t2) {
  const int t = threadIdx.x;
  if (blockIdx.x >= 256) {
    int bx = blockIdx.x - 256;
    int ten = bx >> 6, bxl = bx & 63;
    if (ten == 0 && bxl == 0) {
      float i1 = g1[t] / sqrtf(v1[t] + 1e-5f);
      s1[t] = i1 * (1.f / 9.f);
      t1[t] = b1[t] - m1[t] * i1;
      float i2 = g2[t] / sqrtf(v2[t] + 1e-5f);
      s2[t] = i2 * (1.f / 9.f);
      t2[t] = b2[t] - m2[t] * i2;
    }
    const float4* v = (const float4*)(ten ? w2 : w1);
    float loc = 0.f;
    for (int i = bxl * 256 + t; i < 147456; i += 16384) {
      float4 f = v[i];
      loc = fmaxf(loc, fmaxf(fmaxf(fabsf(f.x), fabsf(f.y)), fmaxf(fabsf(f.z), fabsf(f.w))));
    }
    #pragma unroll
    for (int off = 32; off; off >>= 1) loc = fmaxf(loc, __shfl_xor(loc, off));
    __shared__ float red[4];
    if ((t & 63) == 0) red[t >> 6] = loc;
    __syncthreads();
    if (t == 0)
      partial[ten * 64 + bxl] = fmaxf(fmaxf(red[0], red[1]), fmaxf(red[2], red[3]));
    return;
  }
  __shared__ unsigned au[784 * 17];
  const int n = blockIdx.x >> 2, cq = blockIdx.x & 3;
  const int c4 = t >> 4, q = t & 15;

  // a1 borders (row-major), this cq slice
  #pragma unroll
  for (int m = 0; m < 2; ++m) {
    int s2i = t + m * 256;
    if (s2i < 464) {
      int bp = s2i >> 2, quad = s2i & 3;
      uint4 z = {0, 0, 0, 0};
      *(uint4*)(a1 + ((size_t)n * 900 + border_pix(bp)) * 256 + cq * 64 + quad * 16) = z;
    }
  }
  // a2T borders: slots cq*4 .. cq*4+3 for all 116 border pixels
  #pragma unroll
  for (int m = 0; m < 2; ++m) {
    int s2i = t + m * 256;
    if (s2i < 464) {
      int bp = s2i >> 2, sl = cq * 4 + (s2i & 3);
      uint4 z = {0, 0, 0, 0};
      *(uint4*)(a2T + ((size_t)sl * 57600 + n * 900 + border_pix(bp)) * 16) = z;
    }
  }

  const float* xb = x + (size_t)n * 200704 + (cq * 64 + c4 * 4) * 784;
  #pragma unroll
  for (int k = 0; k < 13; ++k) {
    int hw4 = q + k * 16;
    if (hw4 < 196) {
      unsigned b[4][4];
      #pragma unroll
      for (int i = 0; i < 4; ++i) {
        float4 f = *(const float4*)(xb + i * 784 + hw4 * 4);
        b[i][0] = (unsigned)(int)rintf(3.f * fminf(fmaxf(f.x, 0.f), 1.f));
        b[i][1] = (unsigned)(int)rintf(3.f * fminf(fmaxf(f.y, 0.f), 1.f));
        b[i][2] = (unsigned)(int)rintf(3.f * fminf(fmaxf(f.z, 0.f), 1.f));
        b[i][3] = (unsigned)(int)rintf(3.f * fminf(fmaxf(f.w, 0.f), 1.f));
      }
      #pragma unroll
      for (int j = 0; j < 4; ++j)
        au[(hw4 * 4 + j) * 17 + c4] = b[0][j] | (b[1][j] << 8) | (b[2][j] << 16) | (b[3][j] << 24);
    }
  }
  __syncthreads();
  #pragma unroll
  for (int m = 0; m < 13; ++m) {
    int s = t + m * 256;
    if (s < 3136) {
      int pix = s >> 2, quad = s & 3;
      uint4 v;
      v.x = au[pix * 17 + quad * 4 + 0];
      v.y = au[pix * 17 + quad * 4 + 1];
      v.z = au[pix * 17 + quad * 4 + 2];
      v.w = au[pix * 17 + quad * 4 + 3];
      int hh = pix / 28, ww = pix - hh * 28;
      *(uint4*)(a1 + (((n * 30 + hh + 1) * 30) + ww + 1) * 256 + cq * 64 + quad * 16) = v;
    }
  }
}

// ---- weight quantize: w1 -> wqT1 [kslot][chout][16]; w2 -> row-major ------
__global__ void wquant_k(const float* __restrict__ w1, const float* __restrict__ w2,
                         const float* __restrict__ partial,
                         unsigned char* __restrict__ wqT1, unsigned char* __restrict__ wq2) {
  const int oo = blockIdx.x, ten = blockIdx.y;
  const float* w = ten ? w2 : w1;
  __shared__ float wl[2304];
  const int t = threadIdx.x;
  float pm = partial[ten * 64 + (t & 63)];
  #pragma unroll
  for (int off = 32; off; off >>= 1) pm = fmaxf(pm, __shfl_xor(pm, off));
  const float inv = 1.f / (2.f * tanhf(pm));
  #pragma unroll
  for (int k = 0; k < 9; ++k) wl[k * 256 + t] = tanhf(w[oo * 2304 + k * 256 + t]);
  __syncthreads();
  #pragma unroll
  for (int k = 0; k < 9; ++k) {
    int j = k * 256 + t, t9 = j >> 8, ci = j & 255;
    float tt = wl[ci * 9 + t9] * inv + 0.5f;
    int q = (int)rintf(tt * 3.f);
    unsigned char val = (unsigned char)(signed char)(2 * q - 3);
    if (ten == 0)
      wqT1[(t9 * 16 + (ci >> 4)) * 4096 + oo * 16 + (ci & 15)] = val;
    else
      wq2[oo * 2304 + j] = val;
  }
}

// ---------------------------------------------------------------------------
// conv as implicit GEMM: A staged to LDS (gload16, XOR-swizzled reads),
// B direct global->reg from k-major layout; half-defer wave stagger.
// MODE 0: A=pixels(a1), B=weights(wqT1); epilogue BN1+ReLU+requant -> a2T.
// MODE 1: A=weights(wq2), B=pixels(a2T); epilogue DPP -> f32 NCHW + residual.
// ---------------------------------------------------------------------------
#define LGKM0() do { asm volatile("s_waitcnt lgkmcnt(0)" ::: "memory"); \
  __builtin_amdgcn_sched_barrier(0); } while (0)
#define SP1() __builtin_amdgcn_s_setprio(1)
#define SP0() __builtin_amdgcn_s_setprio(0)

template <int MODE>
__global__ __launch_bounds__(512, 2) void conv_gemm(
    const unsigned char* __restrict__ actA,   // MODE0: a1 ; MODE1: wq2 bytes
    const unsigned char* __restrict__ bsrc,   // MODE0: wqT1; MODE1: a2T
    const float* __restrict__ sC, const float* __restrict__ tC,
    const float* __restrict__ xres, unsigned char* __restrict__ actout,
    float* __restrict__ fout) {
  extern __shared__ __align__(16) char lds[];
  const int tid = threadIdx.x, wv = tid >> 6, lane = tid & 63;
  // bijective XCD swizzle for 196 blocks (q=24, r=4)
  const int bswz = blockIdx.x & 7, bloc = blockIdx.x >> 3;
  const int wg = (bswz < 4 ? bswz * 25 : 100 + (bswz - 4) * 24) + bloc;
  const int pixBase = wg * 256;
  const int wvm = wv >> 2, wvn = wv & 3;
  const bool grpB = (wvm == 1);

  // ---- A staging addresses (rows r covered by all 8 waves) ----
  int aB[2][2];
  {
    int s = (lane & 7) ^ ((lane >> 3) & 7);   // inverse-swizzled source slot
    #pragma unroll
    for (int h = 0; h < 2; ++h)
      #pragma unroll
      for (int c = 0; c < 2; ++c) {
        int r = h * 128 + c * 64 + wv * 8 + (lane >> 3);
        if (MODE == 0) {
          int p = pixBase + r;
          int n = p / 784, rem = p % 784, hh = rem / 28, ww = rem % 28;
          aB[h][c] = (((n * 30 + hh) * 30 + ww) << 8) + (s << 4);
        } else {
          aB[h][c] = r * 2304 + (s << 4);
        }
      }
  }
  auto tofA = [](int kt) {
    int tap = kt >> 1;
    return ((tap / 3) * 30 + (tap % 3)) * 256 + ((kt & 1) << 7);
  };
  auto stageA = [&](int kt) {
    const int koff = (MODE == 0) ? tofA(kt) : kt * 128;
    #pragma unroll
    for (int h = 0; h < 2; ++h) {
      const int base = (kt & 1) * 32768 + h * 16384 + wv * 1024;
      gload16(actA + aB[h][0] + koff, &lds[base]);
      gload16(actA + aB[h][1] + koff, &lds[base + 8192]);
    }
  };

  // ---- B direct-load addresses (per-lane, k-major layouts) ----
  int bB[4];
  #pragma unroll
  for (int q = 0; q < 4; ++q) {
    if (MODE == 0) {
      int ch = wvn * 64 + q * 16 + (lane & 15);
      bB[q] = ch * 16 + (lane >> 4) * 4096;
    } else {
      int p = pixBase + wvn * 64 + q * 16 + (lane & 15);
      int n = p / 784, rem = p % 784, hh = rem / 28, ww = rem % 28;
      // TOP-LEFT of receptive field in padded coords (tap offset added later)
      bB[q] = (n * 900 + hh * 30 + ww) * 16 + (lane >> 4) * 921600;
    }
  }
  i32x4 bc[4][2];
  auto loadB = [&](int kt) {
    const int tap = kt >> 1;
    #pragma unroll
    for (int q = 0; q < 4; ++q)
      #pragma unroll
      for (int kc = 0; kc < 2; ++kc) {
        int off;
        if (MODE == 0)
          off = bB[q] + kt * 32768 + kc * 16384;
        else
          off = bB[q] + ((kt & 1) * 8 + kc * 4) * 921600 +
                ((tap / 3) * 30 + (tap % 3)) * 16;
        bc[q][kc] = *(const i32x4*)(bsrc + off);
      }
  };

  i32x4 acc[8][4];
  #pragma unroll
  for (int i = 0; i < 8; ++i)
    #pragma unroll
    for (int j = 0; j < 4; ++j) acc[i][j] = (i32x4){0, 0, 0, 0};
  i32x4 pa[4][2];

  auto rdA = [&](int buf, int mh) {
    #pragma unroll
    for (int f = 0; f < 4; ++f) {
      int r = wvm * 128 + mh * 64 + f * 16 + (lane & 15);
      int rb = buf * 32768 + r * 128;
      #pragma unroll
      for (int kc = 0; kc < 2; ++kc) {
        int sl = kc * 4 + (lane >> 4);
        pa[f][kc] = *(const i32x4*)&lds[rb + ((sl ^ (r & 7)) << 4)];
      }
    }
  };
  auto quad = [&](int mh, int nh) {
    #pragma unroll
    for (int kc = 0; kc < 2; ++kc)
      #pragma unroll
      for (int f = 0; f < 4; ++f)
        #pragma unroll
        for (int g = 0; g < 2; ++g)
          acc[mh * 4 + f][nh * 2 + g] = __builtin_amdgcn_mfma_i32_16x16x64_i8(
              pa[f][kc], bc[nh * 2 + g][kc], acc[mh * 4 + f][nh * 2 + g], 0, 0, 0);
  };

  // prologue: stage tile 0; collective landing barrier.
  stageA(0);
  asm volatile("s_waitcnt vmcnt(0)" ::: "memory");
  __builtin_amdgcn_sched_barrier(0);
  __builtin_amdgcn_s_barrier();

  for (int t = 0; t < 18; ++t) {
    const int buf = t & 1;
    if (t > 0) {
      // tile handoff: my stage(t)+B drained, my buf(t-1) reads drained;
      // barrier makes it collective -> buf(t-1) parity safe to restage.
      asm volatile("s_waitcnt vmcnt(0) lgkmcnt(0)" ::: "memory");
      __builtin_amdgcn_sched_barrier(0);
      __builtin_amdgcn_s_barrier();
      __builtin_amdgcn_sched_barrier(0);
    }
    if (t <= 16) stageA(t + 1);
    if (grpB && t > 0) {            // deferred tile t-1 (regs only)
      SP1(); quad(1, 0); quad(1, 1); SP0();
    }
    loadB(t);
    rdA(buf, 0);
    LGKM0();
    SP1(); quad(0, 0); quad(0, 1); SP0();
    rdA(buf, 1);
    LGKM0();
    if (!grpB) { SP1(); quad(1, 0); quad(1, 1); SP0(); }
  }
  if (grpB) { SP1(); quad(1, 0); quad(1, 1); SP0(); }

  if (MODE == 0) {
    // BN1 + ReLU + requant; u8 LDS transpose -> a2T (contiguous by pixel)
    float sj[4], tj[4];
    #pragma unroll
    for (int j = 0; j < 4; ++j) {
      int c = wvn * 64 + j * 16 + (lane & 15);
      sj[j] = sC[c]; tj[j] = tC[c];
    }
    __syncthreads();
    #pragma unroll
    for (int i = 0; i < 8; ++i) {
      int lp0 = wvm * 128 + i * 16 + ((lane >> 4) << 2);
      #pragma unroll
      for (int j = 0; j < 4; ++j) {
        int lch = wvn * 64 + j * 16 + (lane & 15);
        #pragma unroll
        for (int r = 0; r < 4; ++r) {
          float y = (float)acc[i][j][r] * sj[j] + tj[j];
          y = fminf(fmaxf(y, 0.f), 1.f);
          int lp = lp0 + r;
          lds[lp * 256 + (lch ^ ((lp & 7) << 4))] = (char)(int)rintf(y * 3.f);
        }
      }
    }
    __syncthreads();
    int rr = tid >> 1, hf = tid & 1;
    int p = pixBase + rr;
    int n = p / 784, rem = p % 784, hh = rem / 28, ww = rem % 28;
    int pixpad = n * 900 + (hh + 1) * 30 + (ww + 1);
    #pragma unroll
    for (int k = 0; k < 8; ++k) {
      uint4 v = *(const uint4*)&lds[rr * 256 + ((hf * 128 + k * 16) ^ ((rr & 7) << 4))];
      *(uint4*)(actout + (size_t)(hf * 8 + k) * 921600 + pixpad * 16) = v;
    }
  } else {
    // BN2 + residual + ReLU via DPP quad_perm 4x4 transpose -> float4 I/O
    #pragma unroll
    for (int i = 0; i < 8; ++i) {
      int c = wvm * 128 + i * 16 + ((lane >> 4) << 2) + (lane & 3);
      float sc = sC[c], tc = tC[c];
      #pragma unroll
      for (int j = 0; j < 4; ++j) {
        int a0 = acc[i][j][0], a1 = acc[i][j][1], a2 = acc[i][j][2], a3 = acc[i][j][3];
        int t0 = __builtin_amdgcn_mov_dpp(a0, 0xB1, 0xF, 0xF, true);
        int t1 = __builtin_amdgcn_mov_dpp(a1, 0xB1, 0xF, 0xF, true);
        int t2 = __builtin_amdgcn_mov_dpp(a2, 0xB1, 0xF, 0xF, true);
        int t3 = __builtin_amdgcn_mov_dpp(a3, 0xB1, 0xF, 0xF, true);
        const bool o1 = (lane & 1) != 0;
        int v0 = o1 ? t1 : a0;
        int v1 = o1 ? a1 : t0;
        int v2 = o1 ? t3 : a2;
        int v3 = o1 ? a3 : t2;
        int u0 = __builtin_amdgcn_mov_dpp(v2, 0x4E, 0xF, 0xF, true);
        int u1 = __builtin_amdgcn_mov_dpp(v3, 0x4E, 0xF, 0xF, true);
        int u2 = __builtin_amdgcn_mov_dpp(v0, 0x4E, 0xF, 0xF, true);
        int u3 = __builtin_amdgcn_mov_dpp(v1, 0x4E, 0xF, 0xF, true);
        const bool o2 = (lane & 2) != 0;
        int z0 = o2 ? u0 : v0;
        int z1 = o2 ? u1 : v1;
        int z2 = o2 ? v2 : u2;
        int z3 = o2 ? v3 : u3;
        int P = pixBase + wvn * 64 + j * 16 + (lane & 12);
        int n = P / 784, rem = P - n * 784;
        size_t addr = (size_t)n * 200704 + (size_t)c * 784 + rem;
        float4 xr = *(const float4*)(xres + addr);
        float4 y;
        y.x = fmaxf((float)z0 * sc + tc + xr.x, 0.f);
        y.y = fmaxf((float)z1 * sc + tc + xr.y, 0.f);
        y.z = fmaxf((float)z2 * sc + tc + xr.z, 0.f);
        y.w = fmaxf((float)z3 * sc + tc + xr.w, 0.f);
        *(float4*)(fout + addr) = y;
      }
    }
  }
}

extern "C" void kernel_launch(void* const* d_in, const int* in_sizes, int n_in,
                              void* d_out, int out_size, void* d_ws, size_t ws_size,
                              hipStream_t stream) {
  const float* x  = (const float*)d_in[0];
  const float* w1 = (const float*)d_in[1];
  const float* g1 = (const float*)d_in[2];
  const float* b1 = (const float*)d_in[3];
  const float* m1 = (const float*)d_in[4];
  const float* v1 = (const float*)d_in[5];
  const float* w2 = (const float*)d_in[6];
  const float* g2 = (const float*)d_in[7];
  const float* b2 = (const float*)d_in[8];
  const float* m2 = (const float*)d_in[9];
  const float* v2 = (const float*)d_in[10];

  char* ws = (char*)d_ws;
  float* partial = (float*)ws;
  float* s1 = (float*)(ws + 1024);
  float* t1 = (float*)(ws + 2048);
  float* s2 = (float*)(ws + 3072);
  float* t2 = (float*)(ws + 4096);
  unsigned char* a1  = (unsigned char*)(ws + 8192);
  unsigned char* a2T = a1 + ABUF;
  unsigned char* wqT1 = a2T + ABUF;
  unsigned char* wq2  = wqT1 + 589824;

  void (*k0)(const unsigned char*, const unsigned char*, const float*, const float*,
             const float*, unsigned char*, float*) = conv_gemm<0>;
  void (*k1)(const unsigned char*, const unsigned char*, const float*, const float*,
             const float*, unsigned char*, float*) = conv_gemm<1>;
  (void)hipFuncSetAttribute((const void*)k0, hipFuncAttributeMaxDynamicSharedMemorySize, 65536);
  (void)hipFuncSetAttribute((const void*)k1, hipFuncAttributeMaxDynamicSharedMemorySize, 65536);

  pre_k<<<384, 256, 0, stream>>>(x, a1, a2T, w1, w2, partial,
                                 g1, b1, m1, v1, g2, b2, m2, v2, s1, t1, s2, t2);
  wquant_k<<<dim3(256, 2), 256, 0, stream>>>(w1, w2, partial, wqT1, wq2);
  conv_gemm<0><<<196, 512, 65536, stream>>>(a1, wqT1, s1, t1, nullptr, a2T, nullptr);
  conv_gemm<1><<<196, 512, 65536, stream>>>(wq2, a2T, s2, t2,
                                            x, nullptr, (float*)d_out);
}